// Round 7
// baseline (827.719 us; speedup 1.0000x reference)
//
#include <hip/hip_runtime.h>
#include <stdint.h>

// MoE FFN: fused router(fp64 logits, hierarchical atomics, fused x-scatter)
// -> W transpose/convert (vectorized stores) -> GEMM1(gelu)
// -> GEMM2(weight + fp32 atomicAdd direct to out, split-K=2; combine fused).
// GEMMs: round-2-proven 256x256 tile, 8 waves (2Mx4N), BK=64, mfma_f32_16x16x32_bf16,
// 8-phase schedule w/ counted vmcnt (T3+T4), source-side LDS XOR swizzle (T2, measured
// 0 bank conflicts), setprio (T5). Garbage prefetch k-tiles CLAMPED in-bounds.

#define NEXP 7
#define KTOP 2
#define CAP 3072
#define DM 1024
#define HF 4096
#define TT 8192
#define RBLK 32   // tokens per router block

typedef __bf16 bf16x8 __attribute__((ext_vector_type(8)));
typedef float f32x4 __attribute__((ext_vector_type(4)));

__device__ __forceinline__ unsigned short f2bf(float v) {
  union { float f; unsigned u; } a; a.f = v;
  unsigned r = a.u + 0x7FFFu + ((a.u >> 16) & 1u);   // RNE
  return (unsigned short)(r >> 16);
}
__device__ __forceinline__ float bf2f(unsigned short h) {
  union { unsigned u; float f; } a; a.u = ((unsigned)h) << 16; return a.f;
}
__device__ __forceinline__ float gelu_t(float v) {
  float u = 0.7978845608028654f * (v + 0.044715f * v * v * v);
  float ex = __expf(2.0f * u);
  float th = 1.0f - 2.0f / (ex + 1.0f);
  return 0.5f * v * (1.0f + th);
}
__device__ __forceinline__ void gl2lds16(const void* g, void* l) {
  __builtin_amdgcn_global_load_lds(
      (const __attribute__((address_space(1))) unsigned int*)g,
      (__attribute__((address_space(3))) unsigned int*)l, 16, 0, 0);
}

__global__ void init_counts(int* counts) {
  if (threadIdx.x < NEXP) counts[threadIdx.x] = 0;
}

__global__ void zero_out(float* __restrict__ out) {
  ((float4*)(out + (long)blockIdx.x * DM))[threadIdx.x] = float4{0.f, 0.f, 0.f, 0.f};
}

// 256 blocks x 32 tokens. Per-block LDS histogram -> 7 global atomics/block.
// Scatter of x into xb fused (x row is L2-hot after logit pass). fp64 top-2.
__global__ __launch_bounds__(256) void router_fused(
    const float* __restrict__ x, const float* __restrict__ Wg,
    int* __restrict__ counts, int* __restrict__ flatSlot,
    int* __restrict__ tokOfSlot, float* __restrict__ wOfSlot,
    unsigned short* __restrict__ xb) {
  __shared__ float sWgT[NEXP][DM];     // transposed gates, 28KB, float4-readable
  __shared__ int hist[NEXP], base[NEXP];
  __shared__ int pickE[RBLK * 2];
  __shared__ int pickR[RBLK * 2];
  __shared__ float pickW[RBLK * 2];
  int tid = threadIdx.x, lane = tid & 63, wave = tid >> 6;

  for (int i = tid; i < NEXP * DM; i += 256) {
    int e = i / DM, d = i - e * DM;
    sWgT[e][d] = Wg[d * NEXP + e];
  }
  if (tid < NEXP) hist[tid] = 0;
  __syncthreads();

  for (int tt = wave; tt < RBLK; tt += 4) {
    int t = blockIdx.x * RBLK + tt;
    const float4* xr = (const float4*)(x + (long)t * DM);
    double acc[NEXP];
#pragma unroll
    for (int e = 0; e < NEXP; ++e) acc[e] = 0.0;
#pragma unroll
    for (int j = 0; j < 4; ++j) {
      float4 xv = xr[j * 64 + lane];
      int d4 = (j * 64 + lane) * 4;
#pragma unroll
      for (int e = 0; e < NEXP; ++e) {
        float4 wv = *(const float4*)&sWgT[e][d4];
        acc[e] += (double)xv.x * (double)wv.x + (double)xv.y * (double)wv.y
                + (double)xv.z * (double)wv.z + (double)xv.w * (double)wv.w;
      }
    }
#pragma unroll
    for (int e = 0; e < NEXP; ++e) {
#pragma unroll
      for (int off = 32; off > 0; off >>= 1) acc[e] += __shfl_down(acc[e], off);
    }
    if (lane == 0) {
      int i1 = 0; double l1 = acc[0];
      for (int e2 = 1; e2 < NEXP; ++e2) if (acc[e2] > l1) { l1 = acc[e2]; i1 = e2; }
      int i2 = -1; double l2 = -1e300;
      for (int e2 = 0; e2 < NEXP; ++e2) if (e2 != i1 && acc[e2] > l2) { l2 = acc[e2]; i2 = e2; }
      float w1 = (float)(1.0 / (1.0 + exp(l2 - l1)));   // softmax top-2 renormalized
      int r0 = atomicAdd(&hist[i1], 1);
      int r1 = atomicAdd(&hist[i2], 1);
      pickE[2 * tt] = i1;     pickR[2 * tt] = r0;     pickW[2 * tt] = w1;
      pickE[2 * tt + 1] = i2; pickR[2 * tt + 1] = r1; pickW[2 * tt + 1] = 1.0f - w1;
    }
  }
  __syncthreads();
  if (tid < NEXP) base[tid] = atomicAdd(&counts[tid], hist[tid]);
  __syncthreads();

  for (int tt = wave; tt < RBLK; tt += 4) {
    int t = blockIdx.x * RBLK + tt;
    const float4* xr = (const float4*)(x + (long)t * DM);
    float4 v0 = xr[0 * 64 + lane], v1 = xr[1 * 64 + lane];
    float4 v2 = xr[2 * 64 + lane], v3 = xr[3 * 64 + lane];
    ushort4 o0, o1, o2, o3;
    o0.x = f2bf(v0.x); o0.y = f2bf(v0.y); o0.z = f2bf(v0.z); o0.w = f2bf(v0.w);
    o1.x = f2bf(v1.x); o1.y = f2bf(v1.y); o1.z = f2bf(v1.z); o1.w = f2bf(v1.w);
    o2.x = f2bf(v2.x); o2.y = f2bf(v2.y); o2.z = f2bf(v2.z); o2.w = f2bf(v2.w);
    o3.x = f2bf(v3.x); o3.y = f2bf(v3.y); o3.z = f2bf(v3.z); o3.w = f2bf(v3.w);
#pragma unroll
    for (int p = 0; p < 2; ++p) {
      int e = pickE[2 * tt + p];
      int s = base[e] + pickR[2 * tt + p];
      int fi = t * 2 + p;
      if (lane == 0) {
        flatSlot[fi] = (s < CAP) ? s : CAP;
        if (s < CAP) { tokOfSlot[e * CAP + s] = fi; wOfSlot[e * CAP + s] = pickW[2 * tt + p]; }
      }
      if (s < CAP) {
        ushort4* dst = (ushort4*)(xb + ((long)e * CAP + s) * DM);
        dst[0 * 64 + lane] = o0; dst[1 * 64 + lane] = o1;
        dst[2 * 64 + lane] = o2; dst[3 * 64 + lane] = o3;
      }
    }
  }
}

// [R][C] fp32 -> [C][R] bf16, 64x64 LDS tile (pad 65 => 2-way/free on both sides).
// Stores vectorized: ushort4 (8B/lane) instead of 2B/lane.
__global__ void transcvt(const float* __restrict__ in, unsigned short* __restrict__ out,
                         int R, int C) {
  __shared__ float tile[64][65];
  long base = (long)blockIdx.z * (long)R * (long)C;
  const float* inp = in + base;
  unsigned short* outp = out + base;
  int c0 = blockIdx.x * 64, r0 = blockIdx.y * 64;
  int lx = threadIdx.x & 63, ly = threadIdx.x >> 6;
#pragma unroll
  for (int i = 0; i < 16; ++i) {
    int r = ly + i * 4;
    tile[r][lx] = inp[(long)(r0 + r) * C + c0 + lx];
  }
  __syncthreads();
  int sx = threadIdx.x & 15;        // r-quad group: rows 4sx..4sx+3
  int sy = threadIdx.x >> 4;        // 0..15
#pragma unroll
  for (int cc = 0; cc < 4; ++cc) {
    int c = cc * 16 + sy;
    ushort4 o;
    o.x = f2bf(tile[4 * sx + 0][c]);
    o.y = f2bf(tile[4 * sx + 1][c]);
    o.z = f2bf(tile[4 * sx + 2][c]);
    o.w = f2bf(tile[4 * sx + 3][c]);
    *(ushort4*)&outp[(long)(c0 + c) * R + r0 + 4 * sx] = o;
  }
}

// ---------------- 256x256 8-phase GEMM (T2+T3+T4+T5) — round-2 proven -------
// C = A[M,LD-rows] @ Bt[N,LD-rows]^T over k in [kstart, kstart+klen).
// EPI=0: gelu->bf16 to Ce; EPI=1: w*val fp32 atomicAdd into out (combine fused).
template <int EPI>
__global__ __launch_bounds__(512, 2) void gemm256(
    const unsigned short* __restrict__ A, const unsigned short* __restrict__ Bt,
    void* __restrict__ Cout, const int* __restrict__ counts,
    const int* __restrict__ tokOfSlot, const float* __restrict__ wOfSlot,
    int LD, int klen, int N, int kspl, long aexps, long cexps) {
  __shared__ __align__(16) unsigned short sAb[2][16384];  // [buf][256 rows x 64 k], 32KB each
  __shared__ __align__(16) unsigned short sBb[2][16384];
  int e = blockIdx.z / kspl, ks = blockIdx.z % kspl;
  int mcnt = counts[e]; mcnt = mcnt < CAP ? mcnt : CAP;
  int m0 = blockIdx.y * 256;
  if (m0 >= mcnt) return;
  int n0 = blockIdx.x * 256;
  long kstart = (long)ks * klen;

  const unsigned short* Ae = A + (long)e * aexps;
  const unsigned short* Be = Bt + (long)e * (long)N * LD;

  int tid = threadIdx.x;
  int lane = tid & 63, wave = tid >> 6;
  int wr = wave >> 2, wc = wave & 3;        // 2M x 4N wave grid
  int lm = lane & 15, quad = lane >> 4;

  // staging: each STA/STB instr covers 64 rows; thread loads 16B.
  // Source k-chunk is XOR-swizzled by row&7 so the linear LDS dest holds a
  // swizzled layout; reads apply the same XOR (involution).
  int srow = tid >> 3;                                  // + 64 per instr
  int scol = ((lane & 7) ^ (lane >> 3)) << 3;           // element offset
  const unsigned short* As = Ae + (long)(m0 + srow) * LD + kstart + scol;
  const unsigned short* Bs = Be + (long)(n0 + srow) * LD + kstart + scol;

  int abase = (wr * 128 + lm) * 64;
  int bbase = (wc * 64 + lm) * 64;
  int cx0 = (quad ^ (lm & 7)) << 3;
  int cx1 = ((quad + 4) ^ (lm & 7)) << 3;

  f32x4 acc[8][4];
#pragma unroll
  for (int i = 0; i < 8; ++i)
#pragma unroll
    for (int j = 0; j < 4; ++j) acc[i][j] = f32x4{0.f, 0.f, 0.f, 0.f};

  int NT = klen >> 6, NI = NT >> 1;   // K-tiles of 64; iterations handle pairs

  // Garbage prefetch clamp: staged tile index never exceeds NT-1 (in-bounds;
  // clamped stages land in buffers that are never consumed afterward).
#define STA(buf, kt, half) do { \
    int _kt = (kt) < NT ? (kt) : (NT - 1); \
    gl2lds16(As + (long)_kt * 64 + (long)((half) * 2) * 64 * LD, \
             &sAb[buf][(half) * 8192 + tid * 8]); \
    gl2lds16(As + (long)_kt * 64 + (long)((half) * 2 + 1) * 64 * LD, \
             &sAb[buf][(half) * 8192 + 4096 + tid * 8]); \
  } while (0)
#define STB(buf, kt, half) do { \
    int _kt = (kt) < NT ? (kt) : (NT - 1); \
    gl2lds16(Bs + (long)_kt * 64 + (long)((half) * 2) * 64 * LD, \
             &sBb[buf][(half) * 8192 + tid * 8]); \
    gl2lds16(Bs + (long)_kt * 64 + (long)((half) * 2 + 1) * 64 * LD, \
             &sBb[buf][(half) * 8192 + 4096 + tid * 8]); \
  } while (0)

  bf16x8 bF[4][2];

#define PHASE(buf, mi0, RB, STAGE, VM) do { \
    bf16x8 a00 = *(const bf16x8*)&sAb[buf][abase + (mi0) * 1024 + cx0]; \
    bf16x8 a01 = *(const bf16x8*)&sAb[buf][abase + (mi0) * 1024 + cx1]; \
    bf16x8 a10 = *(const bf16x8*)&sAb[buf][abase + (mi0) * 1024 + 1024 + cx0]; \
    bf16x8 a11 = *(const bf16x8*)&sAb[buf][abase + (mi0) * 1024 + 1024 + cx1]; \
    if (RB) { \
      _Pragma("unroll") \
      for (int ni = 0; ni < 4; ++ni) { \
        bF[ni][0] = *(const bf16x8*)&sBb[buf][bbase + ni * 1024 + cx0]; \
        bF[ni][1] = *(const bf16x8*)&sBb[buf][bbase + ni * 1024 + cx1]; \
      } \
    } \
    STAGE; \
    __builtin_amdgcn_s_barrier(); \
    asm volatile("s_waitcnt lgkmcnt(0)" ::: "memory"); \
    __builtin_amdgcn_s_setprio(1); \
    _Pragma("unroll") \
    for (int ni = 0; ni < 4; ++ni) { \
      acc[mi0][ni]     = __builtin_amdgcn_mfma_f32_16x16x32_bf16(a00, bF[ni][0], acc[mi0][ni], 0, 0, 0); \
      acc[mi0][ni]     = __builtin_amdgcn_mfma_f32_16x16x32_bf16(a01, bF[ni][1], acc[mi0][ni], 0, 0, 0); \
      acc[mi0 + 1][ni] = __builtin_amdgcn_mfma_f32_16x16x32_bf16(a10, bF[ni][0], acc[mi0 + 1][ni], 0, 0, 0); \
      acc[mi0 + 1][ni] = __builtin_amdgcn_mfma_f32_16x16x32_bf16(a11, bF[ni][1], acc[mi0 + 1][ni], 0, 0, 0); \
    } \
    __builtin_amdgcn_s_setprio(0); \
    VM; \
    __builtin_amdgcn_s_barrier(); \
  } while (0)

  // prologue: buf0 <- tile0 (8 loads), buf1.B <- tile1 (4 loads); keep 4 in flight
  STA(0, 0, 0); STA(0, 0, 1); STB(0, 0, 0); STB(0, 0, 1);
  STB(1, 1, 0); STB(1, 1, 1);
  asm volatile("s_waitcnt vmcnt(4)" ::: "memory");
  __builtin_amdgcn_s_barrier();

  for (int t = 0; t < NI; ++t) {
    int k0 = 2 * t, k1 = 2 * t + 1;
    // phases 1-4: compute tile k0 from buf0
    PHASE(0, 0, 1, STA(1, k1, 0), (void)0);        // B(buf0) -> regs here
    PHASE(0, 2, 0, STA(1, k1, 1), (void)0);
    PHASE(0, 4, 0, STB(0, k0 + 2, 0), (void)0);    // buf0.B free since phase 1
    PHASE(0, 6, 0, STB(0, k0 + 2, 1),
          asm volatile("s_waitcnt vmcnt(4)" ::: "memory"));  // buf1 ready
    // phases 5-8: compute tile k1 from buf1
    PHASE(1, 0, 1, STA(0, k0 + 2, 0), (void)0);    // buf0.A free since phase 4
    PHASE(1, 2, 0, STA(0, k0 + 2, 1), (void)0);
    PHASE(1, 4, 0, STB(1, k1 + 2, 0), (void)0);    // buf1.B free since phase 5
    PHASE(1, 6, 0, STB(1, k1 + 2, 1),
          asm volatile("s_waitcnt vmcnt(4)" ::: "memory"));  // buf0 ready
  }
  asm volatile("s_waitcnt vmcnt(0)" ::: "memory");
#undef PHASE
#undef STA
#undef STB

  // C/D layout: col = lane&15 (N), row = quad*4 + r (M)  [m89-verified]
  if (EPI == 0) {
    unsigned short* Ce = (unsigned short*)Cout + (long)e * cexps;
#pragma unroll
    for (int mi = 0; mi < 8; ++mi) {
      int mb = m0 + wr * 128 + mi * 16 + quad * 4;
#pragma unroll
      for (int r = 0; r < 4; ++r) {
        int m = mb + r;
        if (m < mcnt) {
#pragma unroll
          for (int ni = 0; ni < 4; ++ni) {
            int n = n0 + wc * 64 + ni * 16 + lm;
            Ce[(long)m * N + n] = f2bf(gelu_t(acc[mi][ni][r]));
          }
        }
      }
    }
  } else {
    float* O = (float*)Cout;   // [TT][DM] fp32, zero-initialized; combine fused
#pragma unroll
    for (int mi = 0; mi < 8; ++mi) {
      int mb = m0 + wr * 128 + mi * 16 + quad * 4;
#pragma unroll
      for (int r = 0; r < 4; ++r) {
        int m = mb + r;
        if (m < mcnt) {
          int fi = tokOfSlot[e * CAP + m];
          float w = wOfSlot[e * CAP + m];
          long trow = (long)(fi >> 1) * N;
#pragma unroll
          for (int ni = 0; ni < 4; ++ni) {
            int n = n0 + wc * 64 + ni * 16 + lm;
            atomicAdd(&O[trow + n], w * acc[mi][ni][r]);
          }
        }
      }
    }
  }
}

// --------- legacy 128x128 GEMM kept for the workspace-constrained plan ------
template <int EPI>
__global__ __launch_bounds__(256, 2) void gemm_bt(
    const unsigned short* __restrict__ A, const unsigned short* __restrict__ Bt,
    void* __restrict__ Cout, const int* __restrict__ counts,
    const int* __restrict__ tokOfSlot, const float* __restrict__ wOfSlot,
    int K, int N, int eoff, long aexps, long cexps) {
  __shared__ unsigned short sA[128 * 32];
  __shared__ unsigned short sB[128 * 32];
  int e = eoff + blockIdx.z;
  int mcnt = counts[e]; mcnt = mcnt < CAP ? mcnt : CAP;
  int m0 = blockIdx.y * 128;
  if (m0 >= mcnt) return;
  int n0 = blockIdx.x * 128;
  const unsigned short* Ae = A + (long)blockIdx.z * aexps;
  const unsigned short* Be = Bt + (long)e * (long)N * (long)K;

  int tid = threadIdx.x;
  int lane = tid & 63, wave = tid >> 6;
  int lm = lane & 15, quad = lane >> 4;
  int wm = (wave & 1) * 64, wn = (wave >> 1) * 64;

  int ra = tid >> 2;
  int ca = (tid & 3) * 8;
  const unsigned short* Ab0 = Ae + (long)(m0 + ra) * K + ca;
  const unsigned short* Ab1 = Ae + (long)(m0 + 64 + ra) * K + ca;
  const unsigned short* Bb0 = Be + (long)(n0 + ra) * K + ca;
  const unsigned short* Bb1 = Be + (long)(n0 + 64 + ra) * K + ca;
  unsigned short* sAp0 = &sA[tid * 8];
  unsigned short* sAp1 = &sA[(tid + 256) * 8];
  unsigned short* sBp0 = &sB[tid * 8];
  unsigned short* sBp1 = &sB[(tid + 256) * 8];

  f32x4 acc[4][4];
#pragma unroll
  for (int i = 0; i < 4; ++i)
#pragma unroll
    for (int j = 0; j < 4; ++j) acc[i][j] = f32x4{0.f, 0.f, 0.f, 0.f};

  for (int k0 = 0; k0 < K; k0 += 32) {
    gl2lds16(Ab0 + k0, sAp0);
    gl2lds16(Ab1 + k0, sAp1);
    gl2lds16(Bb0 + k0, sBp0);
    gl2lds16(Bb1 + k0, sBp1);
    __syncthreads();
    bf16x8 aF[4], bFf[4];
#pragma unroll
    for (int mi = 0; mi < 4; ++mi)
      aF[mi] = *(const bf16x8*)&sA[(wm + mi * 16 + lm) * 32 + quad * 8];
#pragma unroll
    for (int ni = 0; ni < 4; ++ni)
      bFf[ni] = *(const bf16x8*)&sB[(wn + ni * 16 + lm) * 32 + quad * 8];
#pragma unroll
    for (int mi = 0; mi < 4; ++mi)
#pragma unroll
      for (int ni = 0; ni < 4; ++ni)
        acc[mi][ni] = __builtin_amdgcn_mfma_f32_16x16x32_bf16(aF[mi], bFf[ni], acc[mi][ni], 0, 0, 0);
    __syncthreads();
  }

  if (EPI == 0) {
    unsigned short* Ce = (unsigned short*)Cout + (long)blockIdx.z * cexps;
#pragma unroll
    for (int mi = 0; mi < 4; ++mi) {
      int mb = m0 + wm + mi * 16 + quad * 4;
#pragma unroll
      for (int r = 0; r < 4; ++r) {
        int m = mb + r;
        if (m < mcnt) {
#pragma unroll
          for (int ni = 0; ni < 4; ++ni) {
            int n = n0 + wn + ni * 16 + lm;
            Ce[(long)m * N + n] = f2bf(gelu_t(acc[mi][ni][r]));
          }
        }
      }
    }
  } else {
    unsigned short* Y = (unsigned short*)Cout;
#pragma unroll
    for (int mi = 0; mi < 4; ++mi) {
      int mb = m0 + wm + mi * 16 + quad * 4;
#pragma unroll
      for (int r = 0; r < 4; ++r) {
        int m = mb + r;
        if (m < mcnt) {
          int fi = tokOfSlot[e * CAP + m];
          float w = wOfSlot[e * CAP + m];
#pragma unroll
          for (int ni = 0; ni < 4; ++ni) {
            int n = n0 + wn + ni * 16 + lm;
            Y[(long)fi * N + n] = f2bf(w * acc[mi][ni][r]);
          }
        }
      }
    }
  }
}

__global__ void combine_k(const unsigned short* __restrict__ yflat,
                          const int* __restrict__ flatSlot, float* __restrict__ out) {
  int t = blockIdx.x;
  bool k0 = flatSlot[2 * t] < CAP, k1 = flatSlot[2 * t + 1] < CAP;
  const ushort4* y0 = (const ushort4*)(yflat + (long)(2 * t) * DM);
  const ushort4* y1 = (const ushort4*)(yflat + (long)(2 * t + 1) * DM);
  ushort4 a = y0[threadIdx.x], b = y1[threadIdx.x];
  float4 r;
  r.x = (k0 ? bf2f(a.x) : 0.f) + (k1 ? bf2f(b.x) : 0.f);
  r.y = (k0 ? bf2f(a.y) : 0.f) + (k1 ? bf2f(b.y) : 0.f);
  r.z = (k0 ? bf2f(a.z) : 0.f) + (k1 ? bf2f(b.z) : 0.f);
  r.w = (k0 ? bf2f(a.w) : 0.f) + (k1 ? bf2f(b.w) : 0.f);
  ((float4*)(out + (long)t * DM))[threadIdx.x] = r;
}

extern "C" void kernel_launch(void* const* d_in, const int* in_sizes, int n_in,
                              void* d_out, int out_size, void* d_ws, size_t ws_size,
                              hipStream_t stream) {
  const float* x  = (const float*)d_in[0];
  const float* Wg = (const float*)d_in[1];
  const float* W1 = (const float*)d_in[2];
  const float* W2 = (const float*)d_in[3];
  float* out = (float*)d_out;

  char* ws = (char*)d_ws;
  size_t off = 0;
  auto alloc = [&](size_t b) { void* p = ws + off; off = (off + b + 255) & ~(size_t)255; return p; };
  int* counts            = (int*)alloc(NEXP * 4);
  int* flatSlot          = (int*)alloc((size_t)TT * KTOP * 4);
  int* tokOfSlot         = (int*)alloc((size_t)NEXP * CAP * 4);
  float* wOfSlot         = (float*)alloc((size_t)NEXP * CAP * 4);
  unsigned short* Wb1    = (unsigned short*)alloc((size_t)NEXP * DM * HF * 2);  // [E][H][D]
  unsigned short* Wb2    = (unsigned short*)alloc((size_t)NEXP * DM * HF * 2);  // [E][D][H]
  unsigned short* xb     = (unsigned short*)alloc((size_t)NEXP * CAP * DM * 2); // [E][CAP][D]
  unsigned short* yflat  = (unsigned short*)alloc((size_t)TT * KTOP * DM * 2);  // planB only
  size_t hbA = (size_t)NEXP * CAP * HF * 2;           // [E][CAP][H]
  size_t hbB = (size_t)CAP * HF * 2;                  // shared per-expert (fallback)
  int planA = (off + hbA) <= ws_size;
  unsigned short* hb = (unsigned short*)alloc(planA ? hbA : hbB);

  init_counts<<<1, 64, 0, stream>>>(counts);
  router_fused<<<TT / RBLK, 256, 0, stream>>>(x, Wg, counts, flatSlot, tokOfSlot, wOfSlot, xb);
  transcvt<<<dim3(HF / 64, DM / 64, NEXP), 256, 0, stream>>>(W1, Wb1, DM, HF);
  transcvt<<<dim3(DM / 64, HF / 64, NEXP), 256, 0, stream>>>(W2, Wb2, HF, DM);

  if (planA) {
    zero_out<<<TT, 256, 0, stream>>>(out);
    // GEMM1: M=CAP,N=HF,K=DM per expert; 16x12x7 = 1344 blocks
    gemm256<0><<<dim3(HF / 256, CAP / 256, NEXP), 512, 0, stream>>>(
        xb, Wb1, hb, counts, tokOfSlot, wOfSlot, DM, DM, HF, 1,
        (long)CAP * DM, (long)CAP * HF);
    // GEMM2: M=CAP,N=DM,K=HF split-K=2; 4x12x14 = 672 blocks; fp32 atomics to out
    gemm256<1><<<dim3(DM / 256, CAP / 256, NEXP * 2), 512, 0, stream>>>(
        hb, Wb2, out, counts, tokOfSlot, wOfSlot, HF, HF / 2, DM, 2,
        (long)CAP * HF, 0);
  } else {
    for (int e = 0; e < NEXP; ++e) {
      gemm_bt<0><<<dim3(HF / 128, CAP / 128, 1), 256, 0, stream>>>(
          xb + (size_t)e * CAP * DM, Wb1, hb, counts, tokOfSlot, wOfSlot, DM, HF, e, 0, 0);
      gemm_bt<1><<<dim3(DM / 128, CAP / 128, 1), 256, 0, stream>>>(
          hb, Wb2, yflat, counts, tokOfSlot, wOfSlot, HF, DM, e, 0, 0);
    }
    combine_k<<<TT, 256, 0, stream>>>(yflat, flatSlot, out);
  }
}

// Round 8
// 765.443 us; speedup vs baseline: 1.0814x; 1.0814x over previous
//
#include <hip/hip_runtime.h>
#include <stdint.h>

// MoE FFN: fused router(fp64 logits, hierarchical atomics, fused x-scatter)
// -> W transpose/convert (vectorized stores) -> GEMM1(gelu)
// -> GEMM2(weight+scatter to bf16 slabs, split-K=2) -> combine_k2.
// GEMMs: round-2/6-proven 256x256 tile, 8 waves (2Mx4N), BK=64, mfma 16x16x32 bf16,
// 8-phase schedule w/ counted vmcnt (T3+T4), source-side LDS XOR swizzle (T2,
// measured 0 bank conflicts), setprio (T5), bijective XCD work remap (T1).
// Garbage prefetch k-tiles CLAMPED in-bounds.

#define NEXP 7
#define KTOP 2
#define CAP 3072
#define DM 1024
#define HF 4096
#define TT 8192
#define RBLK 32   // tokens per router block

typedef __bf16 bf16x8 __attribute__((ext_vector_type(8)));
typedef float f32x4 __attribute__((ext_vector_type(4)));

__device__ __forceinline__ unsigned short f2bf(float v) {
  union { float f; unsigned u; } a; a.f = v;
  unsigned r = a.u + 0x7FFFu + ((a.u >> 16) & 1u);   // RNE
  return (unsigned short)(r >> 16);
}
__device__ __forceinline__ float bf2f(unsigned short h) {
  union { unsigned u; float f; } a; a.u = ((unsigned)h) << 16; return a.f;
}
__device__ __forceinline__ float gelu_t(float v) {
  float u = 0.7978845608028654f * (v + 0.044715f * v * v * v);
  float ex = __expf(2.0f * u);
  float th = 1.0f - 2.0f / (ex + 1.0f);
  return 0.5f * v * (1.0f + th);
}
__device__ __forceinline__ void gl2lds16(const void* g, void* l) {
  __builtin_amdgcn_global_load_lds(
      (const __attribute__((address_space(1))) unsigned int*)g,
      (__attribute__((address_space(3))) unsigned int*)l, 16, 0, 0);
}

__global__ void init_counts(int* counts) {
  if (threadIdx.x < NEXP) counts[threadIdx.x] = 0;
}

// 256 blocks x 32 tokens. Per-block LDS histogram -> 7 global atomics/block.
// Scatter of x into xb fused (x row is L2-hot after logit pass). fp64 top-2.
__global__ __launch_bounds__(256) void router_fused(
    const float* __restrict__ x, const float* __restrict__ Wg,
    int* __restrict__ counts, int* __restrict__ flatSlot,
    int* __restrict__ tokOfSlot, float* __restrict__ wOfSlot,
    unsigned short* __restrict__ xb) {
  __shared__ float sWgT[NEXP][DM];     // transposed gates, 28KB, float4-readable
  __shared__ int hist[NEXP], base[NEXP];
  __shared__ int pickE[RBLK * 2];
  __shared__ int pickR[RBLK * 2];
  __shared__ float pickW[RBLK * 2];
  int tid = threadIdx.x, lane = tid & 63, wave = tid >> 6;

  for (int i = tid; i < NEXP * DM; i += 256) {
    int e = i / DM, d = i - e * DM;
    sWgT[e][d] = Wg[d * NEXP + e];
  }
  if (tid < NEXP) hist[tid] = 0;
  __syncthreads();

  for (int tt = wave; tt < RBLK; tt += 4) {
    int t = blockIdx.x * RBLK + tt;
    const float4* xr = (const float4*)(x + (long)t * DM);
    double acc[NEXP];
#pragma unroll
    for (int e = 0; e < NEXP; ++e) acc[e] = 0.0;
#pragma unroll
    for (int j = 0; j < 4; ++j) {
      float4 xv = xr[j * 64 + lane];
      int d4 = (j * 64 + lane) * 4;
#pragma unroll
      for (int e = 0; e < NEXP; ++e) {
        float4 wv = *(const float4*)&sWgT[e][d4];
        acc[e] += (double)xv.x * (double)wv.x + (double)xv.y * (double)wv.y
                + (double)xv.z * (double)wv.z + (double)xv.w * (double)wv.w;
      }
    }
#pragma unroll
    for (int e = 0; e < NEXP; ++e) {
#pragma unroll
      for (int off = 32; off > 0; off >>= 1) acc[e] += __shfl_down(acc[e], off);
    }
    if (lane == 0) {
      int i1 = 0; double l1 = acc[0];
      for (int e2 = 1; e2 < NEXP; ++e2) if (acc[e2] > l1) { l1 = acc[e2]; i1 = e2; }
      int i2 = -1; double l2 = -1e300;
      for (int e2 = 0; e2 < NEXP; ++e2) if (e2 != i1 && acc[e2] > l2) { l2 = acc[e2]; i2 = e2; }
      float w1 = (float)(1.0 / (1.0 + exp(l2 - l1)));   // softmax top-2 renormalized
      int r0 = atomicAdd(&hist[i1], 1);
      int r1 = atomicAdd(&hist[i2], 1);
      pickE[2 * tt] = i1;     pickR[2 * tt] = r0;     pickW[2 * tt] = w1;
      pickE[2 * tt + 1] = i2; pickR[2 * tt + 1] = r1; pickW[2 * tt + 1] = 1.0f - w1;
    }
  }
  __syncthreads();
  if (tid < NEXP) base[tid] = atomicAdd(&counts[tid], hist[tid]);
  __syncthreads();

  for (int tt = wave; tt < RBLK; tt += 4) {
    int t = blockIdx.x * RBLK + tt;
    const float4* xr = (const float4*)(x + (long)t * DM);
    float4 v0 = xr[0 * 64 + lane], v1 = xr[1 * 64 + lane];
    float4 v2 = xr[2 * 64 + lane], v3 = xr[3 * 64 + lane];
    ushort4 o0, o1, o2, o3;
    o0.x = f2bf(v0.x); o0.y = f2bf(v0.y); o0.z = f2bf(v0.z); o0.w = f2bf(v0.w);
    o1.x = f2bf(v1.x); o1.y = f2bf(v1.y); o1.z = f2bf(v1.z); o1.w = f2bf(v1.w);
    o2.x = f2bf(v2.x); o2.y = f2bf(v2.y); o2.z = f2bf(v2.z); o2.w = f2bf(v2.w);
    o3.x = f2bf(v3.x); o3.y = f2bf(v3.y); o3.z = f2bf(v3.z); o3.w = f2bf(v3.w);
#pragma unroll
    for (int p = 0; p < 2; ++p) {
      int e = pickE[2 * tt + p];
      int s = base[e] + pickR[2 * tt + p];
      int fi = t * 2 + p;
      if (lane == 0) {
        flatSlot[fi] = (s < CAP) ? s : CAP;
        if (s < CAP) { tokOfSlot[e * CAP + s] = fi; wOfSlot[e * CAP + s] = pickW[2 * tt + p]; }
      }
      if (s < CAP) {
        ushort4* dst = (ushort4*)(xb + ((long)e * CAP + s) * DM);
        dst[0 * 64 + lane] = o0; dst[1 * 64 + lane] = o1;
        dst[2 * 64 + lane] = o2; dst[3 * 64 + lane] = o3;
      }
    }
  }
}

// [R][C] fp32 -> [C][R] bf16, 64x64 LDS tile (pad 65 => 2-way/free on both sides).
// Stores vectorized: ushort4 (8B/lane) instead of 2B/lane. (verified round 7)
__global__ void transcvt(const float* __restrict__ in, unsigned short* __restrict__ out,
                         int R, int C) {
  __shared__ float tile[64][65];
  long base = (long)blockIdx.z * (long)R * (long)C;
  const float* inp = in + base;
  unsigned short* outp = out + base;
  int c0 = blockIdx.x * 64, r0 = blockIdx.y * 64;
  int lx = threadIdx.x & 63, ly = threadIdx.x >> 6;
#pragma unroll
  for (int i = 0; i < 16; ++i) {
    int r = ly + i * 4;
    tile[r][lx] = inp[(long)(r0 + r) * C + c0 + lx];
  }
  __syncthreads();
  int sx = threadIdx.x & 15;        // r-quad group: rows 4sx..4sx+3
  int sy = threadIdx.x >> 4;        // 0..15
#pragma unroll
  for (int cc = 0; cc < 4; ++cc) {
    int c = cc * 16 + sy;
    ushort4 o;
    o.x = f2bf(tile[4 * sx + 0][c]);
    o.y = f2bf(tile[4 * sx + 1][c]);
    o.z = f2bf(tile[4 * sx + 2][c]);
    o.w = f2bf(tile[4 * sx + 3][c]);
    *(ushort4*)&outp[(long)(c0 + c) * R + r0 + 4 * sx] = o;
  }
}

// ---------------- 256x256 8-phase GEMM (T1+T2+T3+T4+T5) ---------------------
// C = A[M,LD-rows] @ Bt[N,LD-rows]^T over k in [kstart, kstart+klen).
// EPI=0: gelu->bf16 to Ce; EPI=1: w*val->bf16 scatter to Y slab ks.
template <int EPI>
__global__ __launch_bounds__(512, 2) void gemm256(
    const unsigned short* __restrict__ A, const unsigned short* __restrict__ Bt,
    void* __restrict__ Cout, const int* __restrict__ counts,
    const int* __restrict__ tokOfSlot, const float* __restrict__ wOfSlot,
    int LD, int klen, int N, int kspl, long aexps, long cexps) {
  __shared__ __align__(16) unsigned short sAb[2][16384];  // [buf][256 rows x 64 k], 32KB each
  __shared__ __align__(16) unsigned short sBb[2][16384];

  // T1: bijective XCD work remap (grid sizes here are divisible by 8).
  // Consecutive work ids (same A-panel, x fastest) land on ONE XCD's L2.
  int GX = gridDim.x, GY = gridDim.y;
  int nwg = GX * GY * gridDim.z;
  int f = blockIdx.x + GX * (blockIdx.y + GY * blockIdx.z);
  int w = ((nwg & 7) == 0) ? ((f & 7) * (nwg >> 3) + (f >> 3)) : f;
  int bx = w % GX, byy = (w / GX) % GY, bz = w / (GX * GY);

  int e = bz / kspl, ks = bz % kspl;
  int mcnt = counts[e]; mcnt = mcnt < CAP ? mcnt : CAP;
  int m0 = byy * 256;
  if (m0 >= mcnt) return;
  int n0 = bx * 256;
  long kstart = (long)ks * klen;

  const unsigned short* Ae = A + (long)e * aexps;
  const unsigned short* Be = Bt + (long)e * (long)N * LD;

  int tid = threadIdx.x;
  int lane = tid & 63, wave = tid >> 6;
  int wr = wave >> 2, wc = wave & 3;        // 2M x 4N wave grid
  int lm = lane & 15, quad = lane >> 4;

  // staging: each STA/STB instr covers 64 rows; thread loads 16B.
  // Source k-chunk is XOR-swizzled by row&7 so the linear LDS dest holds a
  // swizzled layout; reads apply the same XOR (involution).
  int srow = tid >> 3;                                  // + 64 per instr
  int scol = ((lane & 7) ^ (lane >> 3)) << 3;           // element offset
  const unsigned short* As = Ae + (long)(m0 + srow) * LD + kstart + scol;
  const unsigned short* Bs = Be + (long)(n0 + srow) * LD + kstart + scol;

  int abase = (wr * 128 + lm) * 64;
  int bbase = (wc * 64 + lm) * 64;
  int cx0 = (quad ^ (lm & 7)) << 3;
  int cx1 = ((quad + 4) ^ (lm & 7)) << 3;

  f32x4 acc[8][4];
#pragma unroll
  for (int i = 0; i < 8; ++i)
#pragma unroll
    for (int j = 0; j < 4; ++j) acc[i][j] = f32x4{0.f, 0.f, 0.f, 0.f};

  int NT = klen >> 6, NI = NT >> 1;   // K-tiles of 64; iterations handle pairs

  // Garbage prefetch clamp: staged tile index never exceeds NT-1 (in-bounds;
  // clamped stages land in buffers that are never consumed afterward).
#define STA(buf, kt, half) do { \
    int _kt = (kt) < NT ? (kt) : (NT - 1); \
    gl2lds16(As + (long)_kt * 64 + (long)((half) * 2) * 64 * LD, \
             &sAb[buf][(half) * 8192 + tid * 8]); \
    gl2lds16(As + (long)_kt * 64 + (long)((half) * 2 + 1) * 64 * LD, \
             &sAb[buf][(half) * 8192 + 4096 + tid * 8]); \
  } while (0)
#define STB(buf, kt, half) do { \
    int _kt = (kt) < NT ? (kt) : (NT - 1); \
    gl2lds16(Bs + (long)_kt * 64 + (long)((half) * 2) * 64 * LD, \
             &sBb[buf][(half) * 8192 + tid * 8]); \
    gl2lds16(Bs + (long)_kt * 64 + (long)((half) * 2 + 1) * 64 * LD, \
             &sBb[buf][(half) * 8192 + 4096 + tid * 8]); \
  } while (0)

  bf16x8 bF[4][2];

#define PHASE(buf, mi0, RB, STAGE, VM) do { \
    bf16x8 a00 = *(const bf16x8*)&sAb[buf][abase + (mi0) * 1024 + cx0]; \
    bf16x8 a01 = *(const bf16x8*)&sAb[buf][abase + (mi0) * 1024 + cx1]; \
    bf16x8 a10 = *(const bf16x8*)&sAb[buf][abase + (mi0) * 1024 + 1024 + cx0]; \
    bf16x8 a11 = *(const bf16x8*)&sAb[buf][abase + (mi0) * 1024 + 1024 + cx1]; \
    if (RB) { \
      _Pragma("unroll") \
      for (int ni = 0; ni < 4; ++ni) { \
        bF[ni][0] = *(const bf16x8*)&sBb[buf][bbase + ni * 1024 + cx0]; \
        bF[ni][1] = *(const bf16x8*)&sBb[buf][bbase + ni * 1024 + cx1]; \
      } \
    } \
    STAGE; \
    __builtin_amdgcn_s_barrier(); \
    asm volatile("s_waitcnt lgkmcnt(0)" ::: "memory"); \
    __builtin_amdgcn_sched_barrier(0); \
    __builtin_amdgcn_s_setprio(1); \
    _Pragma("unroll") \
    for (int ni = 0; ni < 4; ++ni) { \
      acc[mi0][ni]     = __builtin_amdgcn_mfma_f32_16x16x32_bf16(a00, bF[ni][0], acc[mi0][ni], 0, 0, 0); \
      acc[mi0][ni]     = __builtin_amdgcn_mfma_f32_16x16x32_bf16(a01, bF[ni][1], acc[mi0][ni], 0, 0, 0); \
      acc[mi0 + 1][ni] = __builtin_amdgcn_mfma_f32_16x16x32_bf16(a10, bF[ni][0], acc[mi0 + 1][ni], 0, 0, 0); \
      acc[mi0 + 1][ni] = __builtin_amdgcn_mfma_f32_16x16x32_bf16(a11, bF[ni][1], acc[mi0 + 1][ni], 0, 0, 0); \
    } \
    __builtin_amdgcn_s_setprio(0); \
    VM; \
    __builtin_amdgcn_s_barrier(); \
  } while (0)

  // prologue: buf0 <- tile0 (8 loads), buf1.B <- tile1 (4 loads); keep 4 in flight
  STA(0, 0, 0); STA(0, 0, 1); STB(0, 0, 0); STB(0, 0, 1);
  STB(1, 1, 0); STB(1, 1, 1);
  asm volatile("s_waitcnt vmcnt(4)" ::: "memory");
  __builtin_amdgcn_s_barrier();

  for (int t = 0; t < NI; ++t) {
    int k0 = 2 * t, k1 = 2 * t + 1;
    // phases 1-4: compute tile k0 from buf0
    PHASE(0, 0, 1, STA(1, k1, 0), (void)0);        // B(buf0) -> regs here
    PHASE(0, 2, 0, STA(1, k1, 1), (void)0);
    PHASE(0, 4, 0, STB(0, k0 + 2, 0), (void)0);    // buf0.B free since phase 1
    PHASE(0, 6, 0, STB(0, k0 + 2, 1),
          asm volatile("s_waitcnt vmcnt(4)" ::: "memory"));  // buf1 ready
    // phases 5-8: compute tile k1 from buf1
    PHASE(1, 0, 1, STA(0, k0 + 2, 0), (void)0);    // buf0.A free since phase 4
    PHASE(1, 2, 0, STA(0, k0 + 2, 1), (void)0);
    PHASE(1, 4, 0, STB(1, k1 + 2, 0), (void)0);    // buf1.B free since phase 5
    PHASE(1, 6, 0, STB(1, k1 + 2, 1),
          asm volatile("s_waitcnt vmcnt(4)" ::: "memory"));  // buf0 ready
  }
  asm volatile("s_waitcnt vmcnt(0)" ::: "memory");
#undef PHASE
#undef STA
#undef STB

  // C/D layout: col = lane&15 (N), row = quad*4 + r (M)  [m89-verified]
  if (EPI == 0) {
    unsigned short* Ce = (unsigned short*)Cout + (long)e * cexps;
#pragma unroll
    for (int mi = 0; mi < 8; ++mi) {
      int mb = m0 + wr * 128 + mi * 16 + quad * 4;
#pragma unroll
      for (int r = 0; r < 4; ++r) {
        int m = mb + r;
        if (m < mcnt) {
#pragma unroll
          for (int ni = 0; ni < 4; ++ni) {
            int n = n0 + wc * 64 + ni * 16 + lm;
            Ce[(long)m * N + n] = f2bf(gelu_t(acc[mi][ni][r]));
          }
        }
      }
    }
  } else {
    unsigned short* Y = (unsigned short*)Cout + (long)ks * ((long)TT * KTOP * DM);
#pragma unroll
    for (int mi = 0; mi < 8; ++mi) {
      int mb = m0 + wr * 128 + mi * 16 + quad * 4;
#pragma unroll
      for (int r = 0; r < 4; ++r) {
        int m = mb + r;
        if (m < mcnt) {
          int fi = tokOfSlot[e * CAP + m];
          float w = wOfSlot[e * CAP + m];
#pragma unroll
          for (int ni = 0; ni < 4; ++ni) {
            int n = n0 + wc * 64 + ni * 16 + lm;
            Y[(long)fi * N + n] = f2bf(w * acc[mi][ni][r]);
          }
        }
      }
    }
  }
}

// --------- legacy 128x128 GEMM kept for the workspace-constrained plan ------
template <int EPI>
__global__ __launch_bounds__(256, 2) void gemm_bt(
    const unsigned short* __restrict__ A, const unsigned short* __restrict__ Bt,
    void* __restrict__ Cout, const int* __restrict__ counts,
    const int* __restrict__ tokOfSlot, const float* __restrict__ wOfSlot,
    int K, int N, int eoff, long aexps, long cexps) {
  __shared__ unsigned short sA[128 * 32];
  __shared__ unsigned short sB[128 * 32];
  int e = eoff + blockIdx.z;
  int mcnt = counts[e]; mcnt = mcnt < CAP ? mcnt : CAP;
  int m0 = blockIdx.y * 128;
  if (m0 >= mcnt) return;
  int n0 = blockIdx.x * 128;
  const unsigned short* Ae = A + (long)blockIdx.z * aexps;
  const unsigned short* Be = Bt + (long)e * (long)N * (long)K;

  int tid = threadIdx.x;
  int lane = tid & 63, wave = tid >> 6;
  int lm = lane & 15, quad = lane >> 4;
  int wm = (wave & 1) * 64, wn = (wave >> 1) * 64;

  int ra = tid >> 2;
  int ca = (tid & 3) * 8;
  const unsigned short* Ab0 = Ae + (long)(m0 + ra) * K + ca;
  const unsigned short* Ab1 = Ae + (long)(m0 + 64 + ra) * K + ca;
  const unsigned short* Bb0 = Be + (long)(n0 + ra) * K + ca;
  const unsigned short* Bb1 = Be + (long)(n0 + 64 + ra) * K + ca;
  unsigned short* sAp0 = &sA[tid * 8];
  unsigned short* sAp1 = &sA[(tid + 256) * 8];
  unsigned short* sBp0 = &sB[tid * 8];
  unsigned short* sBp1 = &sB[(tid + 256) * 8];

  f32x4 acc[4][4];
#pragma unroll
  for (int i = 0; i < 4; ++i)
#pragma unroll
    for (int j = 0; j < 4; ++j) acc[i][j] = f32x4{0.f, 0.f, 0.f, 0.f};

  for (int k0 = 0; k0 < K; k0 += 32) {
    gl2lds16(Ab0 + k0, sAp0);
    gl2lds16(Ab1 + k0, sAp1);
    gl2lds16(Bb0 + k0, sBp0);
    gl2lds16(Bb1 + k0, sBp1);
    __syncthreads();
    bf16x8 aF[4], bFf[4];
#pragma unroll
    for (int mi = 0; mi < 4; ++mi)
      aF[mi] = *(const bf16x8*)&sA[(wm + mi * 16 + lm) * 32 + quad * 8];
#pragma unroll
    for (int ni = 0; ni < 4; ++ni)
      bFf[ni] = *(const bf16x8*)&sB[(wn + ni * 16 + lm) * 32 + quad * 8];
#pragma unroll
    for (int mi = 0; mi < 4; ++mi)
#pragma unroll
      for (int ni = 0; ni < 4; ++ni)
        acc[mi][ni] = __builtin_amdgcn_mfma_f32_16x16x32_bf16(aF[mi], bFf[ni], acc[mi][ni], 0, 0, 0);
    __syncthreads();
  }

  if (EPI == 0) {
    unsigned short* Ce = (unsigned short*)Cout + (long)blockIdx.z * cexps;
#pragma unroll
    for (int mi = 0; mi < 4; ++mi) {
      int mb = m0 + wm + mi * 16 + quad * 4;
#pragma unroll
      for (int r = 0; r < 4; ++r) {
        int m = mb + r;
        if (m < mcnt) {
#pragma unroll
          for (int ni = 0; ni < 4; ++ni) {
            int n = n0 + wn + ni * 16 + lm;
            Ce[(long)m * N + n] = f2bf(gelu_t(acc[mi][ni][r]));
          }
        }
      }
    }
  } else {
    unsigned short* Y = (unsigned short*)Cout;
#pragma unroll
    for (int mi = 0; mi < 4; ++mi) {
      int mb = m0 + wm + mi * 16 + quad * 4;
#pragma unroll
      for (int r = 0; r < 4; ++r) {
        int m = mb + r;
        if (m < mcnt) {
          int fi = tokOfSlot[e * CAP + m];
          float w = wOfSlot[e * CAP + m];
#pragma unroll
          for (int ni = 0; ni < 4; ++ni) {
            int n = n0 + wn + ni * 16 + lm;
            Y[(long)fi * N + n] = f2bf(w * acc[mi][ni][r]);
          }
        }
      }
    }
  }
}

// combine for split-K=2: sum two bf16 partial slabs per routed slot
__global__ void combine_k2(const unsigned short* __restrict__ yflat,
                           const int* __restrict__ flatSlot, float* __restrict__ out) {
  int t = blockIdx.x;
  bool k0 = flatSlot[2 * t] < CAP, k1 = flatSlot[2 * t + 1] < CAP;
  const long S = (long)TT * KTOP * DM;
  const ushort4* y00 = (const ushort4*)(yflat + (long)(2 * t) * DM);
  const ushort4* y01 = (const ushort4*)(yflat + S + (long)(2 * t) * DM);
  const ushort4* y10 = (const ushort4*)(yflat + (long)(2 * t + 1) * DM);
  const ushort4* y11 = (const ushort4*)(yflat + S + (long)(2 * t + 1) * DM);
  ushort4 a = y00[threadIdx.x], a2 = y01[threadIdx.x];
  ushort4 b = y10[threadIdx.x], b2 = y11[threadIdx.x];
  float4 r;
  r.x = (k0 ? bf2f(a.x) + bf2f(a2.x) : 0.f) + (k1 ? bf2f(b.x) + bf2f(b2.x) : 0.f);
  r.y = (k0 ? bf2f(a.y) + bf2f(a2.y) : 0.f) + (k1 ? bf2f(b.y) + bf2f(b2.y) : 0.f);
  r.z = (k0 ? bf2f(a.z) + bf2f(a2.z) : 0.f) + (k1 ? bf2f(b.z) + bf2f(b2.z) : 0.f);
  r.w = (k0 ? bf2f(a.w) + bf2f(a2.w) : 0.f) + (k1 ? bf2f(b.w) + bf2f(b2.w) : 0.f);
  ((float4*)(out + (long)t * DM))[threadIdx.x] = r;
}

__global__ void combine_k(const unsigned short* __restrict__ yflat,
                          const int* __restrict__ flatSlot, float* __restrict__ out) {
  int t = blockIdx.x;
  bool k0 = flatSlot[2 * t] < CAP, k1 = flatSlot[2 * t + 1] < CAP;
  const ushort4* y0 = (const ushort4*)(yflat + (long)(2 * t) * DM);
  const ushort4* y1 = (const ushort4*)(yflat + (long)(2 * t + 1) * DM);
  ushort4 a = y0[threadIdx.x], b = y1[threadIdx.x];
  float4 r;
  r.x = (k0 ? bf2f(a.x) : 0.f) + (k1 ? bf2f(b.x) : 0.f);
  r.y = (k0 ? bf2f(a.y) : 0.f) + (k1 ? bf2f(b.y) : 0.f);
  r.z = (k0 ? bf2f(a.z) : 0.f) + (k1 ? bf2f(b.z) : 0.f);
  r.w = (k0 ? bf2f(a.w) : 0.f) + (k1 ? bf2f(b.w) : 0.f);
  ((float4*)(out + (long)t * DM))[threadIdx.x] = r;
}

extern "C" void kernel_launch(void* const* d_in, const int* in_sizes, int n_in,
                              void* d_out, int out_size, void* d_ws, size_t ws_size,
                              hipStream_t stream) {
  const float* x  = (const float*)d_in[0];
  const float* Wg = (const float*)d_in[1];
  const float* W1 = (const float*)d_in[2];
  const float* W2 = (const float*)d_in[3];
  float* out = (float*)d_out;

  char* ws = (char*)d_ws;
  size_t off = 0;
  auto alloc = [&](size_t b) { void* p = ws + off; off = (off + b + 255) & ~(size_t)255; return p; };
  int* counts            = (int*)alloc(NEXP * 4);
  int* flatSlot          = (int*)alloc((size_t)TT * KTOP * 4);
  int* tokOfSlot         = (int*)alloc((size_t)NEXP * CAP * 4);
  float* wOfSlot         = (float*)alloc((size_t)NEXP * CAP * 4);
  unsigned short* Wb1    = (unsigned short*)alloc((size_t)NEXP * DM * HF * 2);  // [E][H][D]
  unsigned short* Wb2    = (unsigned short*)alloc((size_t)NEXP * DM * HF * 2);  // [E][D][H]
  unsigned short* xb     = (unsigned short*)alloc((size_t)NEXP * CAP * DM * 2); // [E][CAP][D]
  unsigned short* yflat  = (unsigned short*)alloc((size_t)2 * TT * KTOP * DM * 2); // 2 K-slabs
  size_t hbA = (size_t)NEXP * CAP * HF * 2;           // [E][CAP][H]
  size_t hbB = (size_t)CAP * HF * 2;                  // shared per-expert (fallback)
  int planA = (off + hbA) <= ws_size;
  unsigned short* hb = (unsigned short*)alloc(planA ? hbA : hbB);

  init_counts<<<1, 64, 0, stream>>>(counts);
  router_fused<<<TT / RBLK, 256, 0, stream>>>(x, Wg, counts, flatSlot, tokOfSlot, wOfSlot, xb);
  transcvt<<<dim3(HF / 64, DM / 64, NEXP), 256, 0, stream>>>(W1, Wb1, DM, HF);
  transcvt<<<dim3(DM / 64, HF / 64, NEXP), 256, 0, stream>>>(W2, Wb2, HF, DM);

  if (planA) {
    // GEMM1: M=CAP,N=HF,K=DM per expert; 16x12x7 = 1344 blocks
    gemm256<0><<<dim3(HF / 256, CAP / 256, NEXP), 512, 0, stream>>>(
        xb, Wb1, hb, counts, tokOfSlot, wOfSlot, DM, DM, HF, 1,
        (long)CAP * DM, (long)CAP * HF);
    // GEMM2: M=CAP,N=DM,K=HF split-K=2; 4x12x14 = 672 blocks
    gemm256<1><<<dim3(DM / 256, CAP / 256, NEXP * 2), 512, 0, stream>>>(
        hb, Wb2, yflat, counts, tokOfSlot, wOfSlot, HF, HF / 2, DM, 2,
        (long)CAP * HF, 0);
    combine_k2<<<TT, 256, 0, stream>>>(yflat, flatSlot, out);
  } else {
    for (int e = 0; e < NEXP; ++e) {
      gemm_bt<0><<<dim3(HF / 128, CAP / 128, 1), 256, 0, stream>>>(
          xb + (size_t)e * CAP * DM, Wb1, hb, counts, tokOfSlot, wOfSlot, DM, HF, e, 0, 0);
      gemm_bt<1><<<dim3(DM / 128, CAP / 128, 1), 256, 0, stream>>>(
          hb, Wb2, yflat, counts, tokOfSlot, wOfSlot, HF, DM, e, 0, 0);
    }
    combine_k<<<TT, 256, 0, stream>>>(yflat, flatSlot, out);
  }
}